// Round 4
// baseline (229.788 us; speedup 1.0000x reference)
//
#include <hip/hip_runtime.h>
#include <hip/hip_bf16.h>

// HistogramLoss: two [32,3,512,512] fp32 inputs, per-(B,C) 64-bin histogram
// over [0,1], row-normalized (row count exactly 2^18), L1 mean of diff.
//
// R4: ballot bit-slice histogram (lane L counts bin L) with the 64-bit
// XOR/AND mask tree hand-written in inline asm: v_xor_b32 reads the ballot
// SGPR halves directly (1 SGPR read/instr — legal), v_bcnt_u32_b32 folds the
// accumulate. 24 VALU ops/element vs R2's compiler-generated ~60 (SGPR->VGPR
// moves). No LDS in hot loop, no atomics anywhere: per-block partials in ws
// (1536*64 u32 = 393 KB, fits — R3 proved it), R3's verified epilogue/loss.

#define HW        262144             // 512*512 = 2^18
#define ROWS      96                 // B*C per image
#define NBINS     64
#define BPR       8                  // blocks per row
#define CHUNK     (HW / BPR)         // 32768 elements per block
#define THREADS   256
#define F4_ITERS  (CHUNK / 4 / THREADS)  // 32 float4 per thread
#define NBLOCKS   (2 * ROWS * BPR)   // 1536

__device__ __forceinline__ void count_elem(float c,
                                           unsigned x0, unsigned x1, unsigned x2,
                                           unsigned x3, unsigned x4, unsigned x5,
                                           unsigned& cnt) {
    int bi = (int)(c * 64.0f);
    bi = min(bi, 63);
    unsigned long long m0 = __ballot(bi & 1);
    unsigned long long m1 = __ballot(bi & 2);
    unsigned long long m2 = __ballot(bi & 4);
    unsigned long long m3 = __ballot(bi & 8);
    unsigned long long m4 = __ballot(bi & 16);
    unsigned long long m5 = __ballot(bi & 32);
    unsigned a_lo, a_hi, t_lo, t_hi;
    // lane L: mask of lanes whose bin == L is AND_k (m_k ^ x_k); x_k identical
    // for both 32-bit halves. v_bcnt_u32_b32 d, s0, s1 = popc(s0)+s1.
    asm("v_xor_b32 %[alo], %[m0lo], %[x0]\n\t"
        "v_xor_b32 %[ahi], %[m0hi], %[x0]\n\t"
        "v_xor_b32 %[tlo], %[m1lo], %[x1]\n\t"
        "v_xor_b32 %[thi], %[m1hi], %[x1]\n\t"
        "v_and_b32 %[alo], %[alo], %[tlo]\n\t"
        "v_and_b32 %[ahi], %[ahi], %[thi]\n\t"
        "v_xor_b32 %[tlo], %[m2lo], %[x2]\n\t"
        "v_xor_b32 %[thi], %[m2hi], %[x2]\n\t"
        "v_and_b32 %[alo], %[alo], %[tlo]\n\t"
        "v_and_b32 %[ahi], %[ahi], %[thi]\n\t"
        "v_xor_b32 %[tlo], %[m3lo], %[x3]\n\t"
        "v_xor_b32 %[thi], %[m3hi], %[x3]\n\t"
        "v_and_b32 %[alo], %[alo], %[tlo]\n\t"
        "v_and_b32 %[ahi], %[ahi], %[thi]\n\t"
        "v_xor_b32 %[tlo], %[m4lo], %[x4]\n\t"
        "v_xor_b32 %[thi], %[m4hi], %[x4]\n\t"
        "v_and_b32 %[alo], %[alo], %[tlo]\n\t"
        "v_and_b32 %[ahi], %[ahi], %[thi]\n\t"
        "v_xor_b32 %[tlo], %[m5lo], %[x5]\n\t"
        "v_xor_b32 %[thi], %[m5hi], %[x5]\n\t"
        "v_and_b32 %[alo], %[alo], %[tlo]\n\t"
        "v_and_b32 %[ahi], %[ahi], %[thi]\n\t"
        "v_bcnt_u32_b32 %[cnt], %[alo], %[cnt]\n\t"
        "v_bcnt_u32_b32 %[cnt], %[ahi], %[cnt]"
        : [cnt] "+v"(cnt),
          [alo] "=&v"(a_lo), [ahi] "=&v"(a_hi),
          [tlo] "=&v"(t_lo), [thi] "=&v"(t_hi)
        : [m0lo] "s"((unsigned)m0), [m0hi] "s"((unsigned)(m0 >> 32)),
          [m1lo] "s"((unsigned)m1), [m1hi] "s"((unsigned)(m1 >> 32)),
          [m2lo] "s"((unsigned)m2), [m2hi] "s"((unsigned)(m2 >> 32)),
          [m3lo] "s"((unsigned)m3), [m3hi] "s"((unsigned)(m3 >> 32)),
          [m4lo] "s"((unsigned)m4), [m4hi] "s"((unsigned)(m4 >> 32)),
          [m5lo] "s"((unsigned)m5), [m5hi] "s"((unsigned)(m5 >> 32)),
          [x0] "v"(x0), [x1] "v"(x1), [x2] "v"(x2),
          [x3] "v"(x3), [x4] "v"(x4), [x5] "v"(x5));
}

__global__ __launch_bounds__(THREADS)
void hist_kernel(const float* __restrict__ fake,
                 const float* __restrict__ real,
                 unsigned int* __restrict__ partial) {
    const int tid  = threadIdx.x;
    const int lane = tid & 63;
    const int wv   = tid >> 6;

    // per-lane xor constants: all-ones where lane bit k is 0 (same both halves)
    const unsigned x0 = (lane & 1)  ? 0u : ~0u;
    const unsigned x1 = (lane & 2)  ? 0u : ~0u;
    const unsigned x2 = (lane & 4)  ? 0u : ~0u;
    const unsigned x3 = (lane & 8)  ? 0u : ~0u;
    const unsigned x4 = (lane & 16) ? 0u : ~0u;
    const unsigned x5 = (lane & 32) ? 0u : ~0u;

    const int b     = blockIdx.x;          // 0 .. 1535
    const int chunk = b & (BPR - 1);
    const int rowg  = b >> 3;              // 0..191: img*ROWS + row
    const float* src = (rowg < ROWS) ? fake : real;
    const int row    = (rowg < ROWS) ? rowg : (rowg - ROWS);

    const float4* __restrict__ p =
        (const float4*)(src + (size_t)row * HW + (size_t)chunk * CHUNK);

    unsigned cnt = 0;   // count of bin==lane among this wave's elements

#pragma unroll 4
    for (int i = 0; i < F4_ITERS; ++i) {
        float4 v = p[i * THREADS + tid];
        count_elem(v.x, x0, x1, x2, x3, x4, x5, cnt);
        count_elem(v.y, x0, x1, x2, x3, x4, x5, cnt);
        count_elem(v.z, x0, x1, x2, x3, x4, x5, cnt);
        count_elem(v.w, x0, x1, x2, x3, x4, x5, cnt);
    }

    // combine 4 waves, write per-block partials (plain store, no atomics)
    __shared__ unsigned int comb[4][NBINS];
    comb[wv][lane] = cnt;
    __syncthreads();
    if (tid < NBINS) {
        unsigned s = comb[0][tid] + comb[1][tid] + comb[2][tid] + comb[3][tid];
        partial[(size_t)b * NBINS + tid] = s;
    }
}

__global__ __launch_bounds__(1024)
void loss_kernel(const unsigned int* __restrict__ partial,
                 float* __restrict__ out) {
    const int tid = threadIdx.x;
    int acc = 0;
#pragma unroll
    for (int q = 0; q < 6; ++q) {
        const int pIdx = q * 1024 + tid;     // 0..6143
        const int r  = pIdx >> 6;
        const int bb = pIdx & 63;
        unsigned cf = 0, cr = 0;
#pragma unroll
        for (int c = 0; c < BPR; ++c) {
            cf += partial[((r * BPR + c) * NBINS) + bb];
            cr += partial[(((ROWS + r) * BPR + c) * NBINS) + bb];
        }
        int d = (int)cf - (int)cr;
        acc += (d < 0) ? -d : d;
    }
#pragma unroll
    for (int off = 32; off > 0; off >>= 1)
        acc += __shfl_down(acc, off, 64);
    __shared__ int wsum[16];
    if ((tid & 63) == 0) wsum[tid >> 6] = acc;
    __syncthreads();
    if (tid == 0) {
        long long total = 0;
#pragma unroll
        for (int k = 0; k < 16; ++k) total += wsum[k];
        out[0] = (float)((double)total / (262144.0 * 6144.0));
    }
}

extern "C" void kernel_launch(void* const* d_in, const int* in_sizes, int n_in,
                              void* d_out, int out_size, void* d_ws, size_t ws_size,
                              hipStream_t stream) {
    const float* fake = (const float*)d_in[0];
    const float* real = (const float*)d_in[1];
    unsigned int* partial = (unsigned int*)d_ws;  // 1536*64 u32 = 393216 B
    float* out = (float*)d_out;

    hist_kernel<<<NBLOCKS, THREADS, 0, stream>>>(fake, real, partial);
    loss_kernel<<<1, 1024, 0, stream>>>(partial, out);
}

// Round 5
// 219.438 us; speedup vs baseline: 1.0472x; 1.0472x over previous
//
#include <hip/hip_runtime.h>
#include <hip/hip_bf16.h>

// HistogramLoss: two [32,3,512,512] fp32 inputs, per-(B,C) 64-bin histogram
// over [0,1], row-normalized (row count exactly 2^18), L1 mean of diff.
//
// R5: fire-and-forget LDS atomics to near-private regions. R3's byte-RMW was
// latency-chain bound (ds_read->wait->add->ds_write, in-order, ~60cy/elem);
// R1's shared-subhist atomics were same-address+bank serialization bound;
// R2/R4 ballots are VALU-hazard bound at ~74 instr/group. ds_add_u32 with no
// return has NO dependent chain: 4 threads share one 65-word-pitch region
// (same-(region,bin) collision ~1.5/wave-op, 2-way free; banks uniform via
// odd pitch). DS cost ~10us, VALU ~3us, memory ~33us -> memory-bound.
// 17.7KB LDS -> all 6 blocks/CU resident. Exact integer counting (absmax 0).

#define HW        262144             // 512*512 = 2^18
#define ROWS      96                 // B*C per image
#define NBINS     64
#define BPR       8                  // blocks per row
#define CHUNK     (HW / BPR)         // 32768 elements per block
#define THREADS   256
#define F4_ITERS  (CHUNK / 4 / THREADS)  // 32 float4 per thread
#define NBLOCKS   (2 * ROWS * BPR)   // 1536
#define NREG      64                 // counter regions (4 threads share one)
#define PITCH     65                 // u32 words per region (odd -> banks spread)
#define PRIV_W    (NREG * PITCH)     // 4160 words

__global__ __launch_bounds__(THREADS)
void hist_kernel(const float* __restrict__ fake,
                 const float* __restrict__ real,
                 unsigned int* __restrict__ partial) {
    __shared__ unsigned int priv[PRIV_W];
    __shared__ unsigned int comb[4][NBINS];

    const int tid  = threadIdx.x;
    const int lane = tid & 63;
    const int wv   = tid >> 6;

    for (int k = tid; k < PRIV_W; k += THREADS) priv[k] = 0u;
    __syncthreads();

    const int b     = blockIdx.x;          // 0 .. 1535
    const int chunk = b & (BPR - 1);
    const int rowg  = b >> 3;              // 0..191: img*ROWS + row
    const float* src = (rowg < ROWS) ? fake : real;
    const int row    = (rowg < ROWS) ? rowg : (rowg - ROWS);

    const float4* __restrict__ p =
        (const float4*)(src + (size_t)row * HW + (size_t)chunk * CHUNK);

    unsigned int* __restrict__ reg = &priv[(tid >> 2) * PITCH];

#pragma unroll 4
    for (int i = 0; i < F4_ITERS; ++i) {
        float4 v = p[i * THREADS + tid];
        int b0 = min((int)(v.x * 64.0f), 63);
        int b1 = min((int)(v.y * 64.0f), 63);
        int b2 = min((int)(v.z * 64.0f), 63);
        int b3 = min((int)(v.w * 64.0f), 63);
        // no-return ds_add: no dependent chain, loads run ahead
        atomicAdd(&reg[b0], 1u);
        atomicAdd(&reg[b1], 1u);
        atomicAdd(&reg[b2], 1u);
        atomicAdd(&reg[b3], 1u);
    }
    __syncthreads();

    // wave wv, lane L: sum bin L over regions wv*16..wv*16+15.
    // word = r*65 + lane: lanes consecutive -> banks consecutive, conflict-free.
    unsigned cnt = 0;
#pragma unroll
    for (int r = 0; r < 16; ++r)
        cnt += priv[(wv * 16 + r) * PITCH + lane];
    comb[wv][lane] = cnt;
    __syncthreads();

    if (tid < NBINS) {
        unsigned s = comb[0][tid] + comb[1][tid] + comb[2][tid] + comb[3][tid];
        partial[(size_t)b * NBINS + tid] = s;   // plain store, no global atomics
    }
}

__global__ __launch_bounds__(1024)
void loss_kernel(const unsigned int* __restrict__ partial,
                 float* __restrict__ out) {
    const int tid = threadIdx.x;
    int acc = 0;
#pragma unroll
    for (int q = 0; q < 6; ++q) {
        const int pIdx = q * 1024 + tid;     // 0..6143
        const int r  = pIdx >> 6;
        const int bb = pIdx & 63;
        unsigned cf = 0, cr = 0;
#pragma unroll
        for (int c = 0; c < BPR; ++c) {
            cf += partial[((r * BPR + c) * NBINS) + bb];
            cr += partial[(((ROWS + r) * BPR + c) * NBINS) + bb];
        }
        int d = (int)cf - (int)cr;
        acc += (d < 0) ? -d : d;
    }
#pragma unroll
    for (int off = 32; off > 0; off >>= 1)
        acc += __shfl_down(acc, off, 64);
    __shared__ int wsum[16];
    if ((tid & 63) == 0) wsum[tid >> 6] = acc;
    __syncthreads();
    if (tid == 0) {
        long long total = 0;
#pragma unroll
        for (int k = 0; k < 16; ++k) total += wsum[k];
        out[0] = (float)((double)total / (262144.0 * 6144.0));
    }
}

extern "C" void kernel_launch(void* const* d_in, const int* in_sizes, int n_in,
                              void* d_out, int out_size, void* d_ws, size_t ws_size,
                              hipStream_t stream) {
    const float* fake = (const float*)d_in[0];
    const float* real = (const float*)d_in[1];
    unsigned int* partial = (unsigned int*)d_ws;  // 1536*64 u32 = 393216 B
    float* out = (float*)d_out;

    hist_kernel<<<NBLOCKS, THREADS, 0, stream>>>(fake, real, partial);
    loss_kernel<<<1, 1024, 0, stream>>>(partial, out);
}